// Round 10
// baseline (182.909 us; speedup 1.0000x reference)
//
#include <hip/hip_runtime.h>
#include <math.h>

#define MPTS 8192
#define DIMS 32
#define QB   32      // queries per block (2 B-frags per lane)

typedef __bf16 bf16x8 __attribute__((ext_vector_type(8)));
typedef float  f32x4  __attribute__((ext_vector_type(4)));

// Insert v into sorted-DESCENDING top-4 (t0>=t1>=t2>=t3): 1 max + 3 med3.
__device__ __forceinline__ void top4L_insert(float v, float& t0, float& t1, float& t2, float& t3) {
    float n0 = fmaxf(t0, v);
    float n1 = __builtin_amdgcn_fmed3f(v, t0, t1);
    float n2 = __builtin_amdgcn_fmed3f(v, t1, t2);
    float n3 = __builtin_amdgcn_fmed3f(v, t2, t3);
    t0 = n0; t1 = n1; t2 = n2; t3 = n3;
}

// Merge quad-partner top-4 lists in-register (lanes l and l^mask hold lists
// for the same query when mask is 16 or 32).
__device__ __forceinline__ void merge_shfl(float& t0, float& t1, float& t2, float& t3, int mask) {
    float o0 = __shfl_xor(t0, mask), o1 = __shfl_xor(t1, mask);
    float o2 = __shfl_xor(t2, mask), o3 = __shfl_xor(t3, mask);
    top4L_insert(o0, t0, t1, t2, t3);
    top4L_insert(o1, t0, t1, t2, t3);
    top4L_insert(o2, t0, t1, t2, t3);
    top4L_insert(o3, t0, t1, t2, t3);
}

__device__ __forceinline__ unsigned short f32_to_bf16_rne(float x) {
    unsigned u = __float_as_uint(x);
    unsigned r = u + 0x7FFFu + ((u >> 16) & 1u);
    return (unsigned short)(r >> 16);
}

// K1: bf16 conversion of P,Q + norms pre-scaled by -0.5 ( -|x|^2/2 ).
__global__ void prep_kernel(const float* __restrict__ P, const float* __restrict__ Q,
                            unsigned short* __restrict__ Phi, unsigned short* __restrict__ Qhi,
                            float* __restrict__ normP, float* __restrict__ normQ) {
    int t = blockIdx.x * 256 + threadIdx.x;          // 0 .. 65535
    int mat = t >> 15;                               // 0 = P, 1 = Q
    int idx = t & 32767;
    int r = idx >> 2, seg = idx & 3;                 // 8 elements per thread
    const float* X = mat ? Q : P;
    unsigned short* Xhi = mat ? Qhi : Phi;
    float* nX = mat ? normQ : normP;

    const float* src = X + (size_t)r * DIMS + seg * 8;
    float4 v0 = *(const float4*)(src);
    float4 v1 = *(const float4*)(src + 4);
    float f[8] = {v0.x, v0.y, v0.z, v0.w, v1.x, v1.y, v1.z, v1.w};

    float p = 0.f;
#pragma unroll
    for (int k = 0; k < 8; ++k) p = fmaf(f[k], f[k], p);
    p += __shfl_xor(p, 1);
    p += __shfl_xor(p, 2);      // seg groups of 4 are lane-aligned
    if (seg == 0) nX[r] = -0.5f * p;

    unsigned short h[8];
#pragma unroll
    for (int k = 0; k < 8; ++k) h[k] = f32_to_bf16_rne(f[k]);
    uint4 ph;
    ph.x = (unsigned)h[0] | ((unsigned)h[1] << 16);
    ph.y = (unsigned)h[2] | ((unsigned)h[3] << 16);
    ph.z = (unsigned)h[4] | ((unsigned)h[5] << 16);
    ph.w = (unsigned)h[6] | ((unsigned)h[7] << 16);
    *(uint4*)(Xhi + (size_t)r * DIMS + seg * 8) = ph;
}

// K2: fused knn+count, explicitly software-pipelined. grid (MPTS/QB, 2) =
// 512 blocks, 1024 thr = 16 waves, 2 blocks/CU (100% wave capacity).
// Each iteration PREFETCHES the next 2 row-loads + 2 norm-loads into
// registers before processing the current buffer, so the ~200-cyc L2 load
// latency overlaps the MFMA+insert body. s-domain: s = dot - na/2.
__global__ __launch_bounds__(1024, 8)
void fused_kernel(const unsigned short* __restrict__ Phi, const unsigned short* __restrict__ Qhi,
                  const float* __restrict__ normP, const float* __restrict__ normQ,
                  float* __restrict__ nusqP, float* __restrict__ nusqQ,
                  int* __restrict__ countP, int* __restrict__ countQ) {
    __shared__ float4 ldsM[QB * 17];     // 8.7 KB: [query][wave], +1 pad
    __shared__ float  ldsTau[QB];
    __shared__ int    ldsC[QB * 17];     // 2.2 KB
    const unsigned short *Yhi, *Xhi; const float *nY, *nX; float* nusqOut; int* cntOut;
    if (blockIdx.y == 0) { Yhi = Qhi; nY = normQ; Xhi = Phi; nX = normP;
                           nusqOut = nusqQ; cntOut = countQ; }   // k_p for div_p
    else                 { Yhi = Phi; nY = normP; Xhi = Qhi; nX = normQ;
                           nusqOut = nusqP; cntOut = countP; }
    const int tid = threadIdx.x;
    const int w = tid >> 6, l = tid & 63, q = l & 15, quad = l >> 4;
    const int q0 = blockIdx.x * QB;

    bf16x8 bh0 = *(const bf16x8*)(Yhi + (size_t)(q0 + q) * DIMS + quad * 8);
    bf16x8 bh1 = *(const bf16x8*)(Yhi + (size_t)(q0 + 16 + q) * DIMS + quad * 8);

    // ---------- phase 1: knn over Y (pipelined) ----------
    float t0[2], t1[2], t2[2], t3[2];
#pragma unroll
    for (int b = 0; b < 2; ++b) t0[b] = t1[b] = t2[b] = t3[b] = -3.4e38f;
    {
        const unsigned short* pH = Yhi + ((size_t)(w * 512) + q) * DIMS + quad * 8;
        const float* pN = nY + w * 512 + quad * 4;
        bf16x8 ch0 = *(const bf16x8*)(pH);
        bf16x8 ch1 = *(const bf16x8*)(pH + 16 * DIMS);
        float4 cn0 = *(const float4*)(pN);
        float4 cn1 = *(const float4*)(pN + 16);
#pragma unroll 2
        for (int i = 0; i < 16; ++i) {
            bf16x8 nh0, nh1; float4 nn0, nn1;
            if (i != 15) {                            // uniform scalar branch
                pH += 32 * DIMS; pN += 32;
                nh0 = *(const bf16x8*)(pH);
                nh1 = *(const bf16x8*)(pH + 16 * DIMS);
                nn0 = *(const float4*)(pN);
                nn1 = *(const float4*)(pN + 16);
            }
            f32x4 c0v = {cn0.x, cn0.y, cn0.z, cn0.w};
            f32x4 c1v = {cn1.x, cn1.y, cn1.z, cn1.w};
            f32x4 a0 = __builtin_amdgcn_mfma_f32_16x16x32_bf16(ch0, bh0, c0v, 0, 0, 0);
            f32x4 a1 = __builtin_amdgcn_mfma_f32_16x16x32_bf16(ch0, bh1, c0v, 0, 0, 0);
            f32x4 a2 = __builtin_amdgcn_mfma_f32_16x16x32_bf16(ch1, bh0, c1v, 0, 0, 0);
            f32x4 a3 = __builtin_amdgcn_mfma_f32_16x16x32_bf16(ch1, bh1, c1v, 0, 0, 0);
#pragma unroll
            for (int r = 0; r < 4; ++r) {
                top4L_insert(a0[r], t0[0], t1[0], t2[0], t3[0]);
                top4L_insert(a1[r], t0[1], t1[1], t2[1], t3[1]);
            }
#pragma unroll
            for (int r = 0; r < 4; ++r) {
                top4L_insert(a2[r], t0[0], t1[0], t2[0], t3[0]);
                top4L_insert(a3[r], t0[1], t1[1], t2[1], t3[1]);
            }
            ch0 = nh0; ch1 = nh1; cn0 = nn0; cn1 = nn1;
        }
    }
    // in-wave quad merge: 4 lists -> 1 per (wave, query)
#pragma unroll
    for (int b = 0; b < 2; ++b) {
        merge_shfl(t0[b], t1[b], t2[b], t3[b], 16);
        merge_shfl(t0[b], t1[b], t2[b], t3[b], 32);
    }
    if (quad == 0) {
        ldsM[q * 17 + w]        = make_float4(t0[0], t1[0], t2[0], t3[0]);
        ldsM[(q + 16) * 17 + w] = make_float4(t0[1], t1[1], t2[1], t3[1]);
    }
    __syncthreads();
    if (tid < QB) {
        float a0 = -3.4e38f, a1 = a0, a2 = a0, a3 = a0;
#pragma unroll
        for (int c = 0; c < 16; ++c) {
            float4 v = ldsM[tid * 17 + c];
            top4L_insert(v.x, a0, a1, a2, a3);
            top4L_insert(v.y, a0, a1, a2, a3);
            top4L_insert(v.z, a0, a1, a2, a3);
            top4L_insert(v.w, a0, a1, a2, a3);
        }
        float nb = -2.0f * nY[q0 + tid];               // |y|^2
        float nu2 = fmaxf(nb - 2.0f * a3, 1e-12f);     // sq-domain nu^2, clamped
        nusqOut[q0 + tid] = nu2;
        ldsTau[tid] = 0.5f * (nb - nu2);               // s-domain threshold
    }
    __syncthreads();
    const float tau0 = ldsTau[q], tau1 = ldsTau[q + 16];

    // ---------- phase 2: count over X (pipelined) ----------
    int cnt0 = 0, cnt1 = 0;
    {
        const unsigned short* pH = Xhi + ((size_t)(w * 512) + q) * DIMS + quad * 8;
        const float* pN = nX + w * 512 + quad * 4;
        bf16x8 ch0 = *(const bf16x8*)(pH);
        bf16x8 ch1 = *(const bf16x8*)(pH + 16 * DIMS);
        float4 cn0 = *(const float4*)(pN);
        float4 cn1 = *(const float4*)(pN + 16);
#pragma unroll 2
        for (int i = 0; i < 16; ++i) {
            bf16x8 nh0, nh1; float4 nn0, nn1;
            if (i != 15) {
                pH += 32 * DIMS; pN += 32;
                nh0 = *(const bf16x8*)(pH);
                nh1 = *(const bf16x8*)(pH + 16 * DIMS);
                nn0 = *(const float4*)(pN);
                nn1 = *(const float4*)(pN + 16);
            }
            f32x4 c0v = {cn0.x, cn0.y, cn0.z, cn0.w};
            f32x4 c1v = {cn1.x, cn1.y, cn1.z, cn1.w};
            f32x4 a0 = __builtin_amdgcn_mfma_f32_16x16x32_bf16(ch0, bh0, c0v, 0, 0, 0);
            f32x4 a1 = __builtin_amdgcn_mfma_f32_16x16x32_bf16(ch0, bh1, c0v, 0, 0, 0);
            f32x4 a2 = __builtin_amdgcn_mfma_f32_16x16x32_bf16(ch1, bh0, c1v, 0, 0, 0);
            f32x4 a3 = __builtin_amdgcn_mfma_f32_16x16x32_bf16(ch1, bh1, c1v, 0, 0, 0);
#pragma unroll
            for (int r = 0; r < 4; ++r) {
                cnt0 += (a0[r] >= tau0) ? 1 : 0;
                cnt1 += (a1[r] >= tau1) ? 1 : 0;
                cnt0 += (a2[r] >= tau0) ? 1 : 0;
                cnt1 += (a3[r] >= tau1) ? 1 : 0;
            }
            ch0 = nh0; ch1 = nh1; cn0 = nn0; cn1 = nn1;
        }
    }
    // in-wave quad reduce
    cnt0 += __shfl_xor(cnt0, 16); cnt0 += __shfl_xor(cnt0, 32);
    cnt1 += __shfl_xor(cnt1, 16); cnt1 += __shfl_xor(cnt1, 32);
    if (quad == 0) {
        ldsC[q * 17 + w]        = cnt0;
        ldsC[(q + 16) * 17 + w] = cnt1;
    }
    __syncthreads();
    if (tid < QB) {
        int s = 0;
#pragma unroll
        for (int c = 0; c < 16; ++c) s += ldsC[tid * 17 + c];
        cntOut[q0 + tid] = s;
    }
}

// K3: epilogue with wave-shuffle reductions (exact fp32 clip/pow semantics).
__global__ __launch_bounds__(512)
void final_kernel(const int* __restrict__ countP, const int* __restrict__ countQ,
                  const float* __restrict__ nusqP, const float* __restrict__ nusqQ,
                  float* __restrict__ out) {
    __shared__ int    riQ[8], riP[8];
    __shared__ double rdQ[8], rdP[8];
    const int tid = threadIdx.x;
    const int w = tid >> 6, l = tid & 63;

    int sQ = 0, sP = 0;
    for (int j = tid; j < MPTS; j += 512) { sQ += countQ[j]; sP += countP[j]; }
#pragma unroll
    for (int o = 32; o > 0; o >>= 1) { sQ += __shfl_down(sQ, o); sP += __shfl_down(sP, o); }
    if (l == 0) { riQ[w] = sQ; riP[w] = sP; }
    __syncthreads();
    int totQ = 0, totP = 0;
#pragma unroll
    for (int u = 0; u < 8; ++u) { totQ += riQ[u]; totP += riP[u]; }

    const float kq_term = 3.0f / 24576.0f;
    float kpQ = (float)totQ + 1e-20f;
    float kpP = (float)totP + 1e-20f;
    double rQ = 0.0, rP = 0.0;
    for (int j = tid; j < MPTS; j += 512) {
        {
            float nu = sqrtf(nusqQ[j]);
            float x = nu * nu; x *= x; x *= x; x *= x; x *= x;   // nu^32
            float inv = 1.0f / (x + 1e-20f);
            float p_den = ((float)countQ[j] / kpQ) * inv;
            p_den = fminf(fmaxf(p_den, 1e-20f), 1e10f);
            float q_den = kq_term * inv;
            q_den = fminf(fmaxf(q_den, 1e-20f), 1e10f);
            rQ += (double)((p_den / q_den) * kq_term);
        }
        {
            float nu = sqrtf(nusqP[j]);
            float x = nu * nu; x *= x; x *= x; x *= x; x *= x;
            float inv = 1.0f / (x + 1e-20f);
            float p_den = ((float)countP[j] / kpP) * inv;
            p_den = fminf(fmaxf(p_den, 1e-20f), 1e10f);
            float q_den = kq_term * inv;
            q_den = fminf(fmaxf(q_den, 1e-20f), 1e10f);
            rP += (double)((p_den / q_den) * kq_term);
        }
    }
#pragma unroll
    for (int o = 32; o > 0; o >>= 1) { rQ += __shfl_down(rQ, o); rP += __shfl_down(rP, o); }
    if (l == 0) { rdQ[w] = rQ; rdP[w] = rP; }
    __syncthreads();
    if (tid == 0) {
        double RQ = 0.0, RP = 0.0;
#pragma unroll
        for (int u = 0; u < 8; ++u) { RQ += rdQ[u]; RP += rdP[u]; }
        float divP = fmaxf(0.0f, logf((float)RQ));    // alpha=2 -> 1/(alpha-1)=1
        float divQ = fmaxf(0.0f, logf((float)RP));
        out[0] = fmaxf(divP, divQ);
    }
}

extern "C" void kernel_launch(void* const* d_in, const int* in_sizes, int n_in,
                              void* d_out, int out_size, void* d_ws, size_t ws_size,
                              hipStream_t stream) {
    const float* P = (const float*)d_in[0];
    const float* Q = (const float*)d_in[1];
    float* out = (float*)d_out;

    unsigned short* Phi = (unsigned short*)d_ws;
    unsigned short* Qhi = Phi + MPTS * DIMS;
    float* normP = (float*)(Qhi + MPTS * DIMS);
    float* normQ = normP + MPTS;
    float* nusqP = normQ + MPTS;
    float* nusqQ = nusqP + MPTS;
    int* countP  = (int*)(nusqQ + MPTS);
    int* countQ  = countP + MPTS;

    prep_kernel<<<256, 256, 0, stream>>>(P, Q, Phi, Qhi, normP, normQ);
    fused_kernel<<<dim3(MPTS / QB, 2), 1024, 0, stream>>>(Phi, Qhi, normP, normQ,
                                                          nusqP, nusqQ, countP, countQ);
    final_kernel<<<1, 512, 0, stream>>>(countP, countQ, nusqP, nusqQ, out);
}

// Round 11
// 118.829 us; speedup vs baseline: 1.5393x; 1.5393x over previous
//
#include <hip/hip_runtime.h>
#include <math.h>

#define MPTS 8192
#define DIMS 32
#define QB   64      // queries per block (4 B-frags per lane)
#define ZSP  4       // candidate-dimension split

typedef __bf16 bf16x8 __attribute__((ext_vector_type(8)));
typedef float  f32x4  __attribute__((ext_vector_type(4)));

// Insert v into sorted-DESCENDING top-4 (t0>=t1>=t2>=t3): 1 max + 3 med3.
__device__ __forceinline__ void top4L_insert(float v, float& t0, float& t1, float& t2, float& t3) {
    float n0 = fmaxf(t0, v);
    float n1 = __builtin_amdgcn_fmed3f(v, t0, t1);
    float n2 = __builtin_amdgcn_fmed3f(v, t1, t2);
    float n3 = __builtin_amdgcn_fmed3f(v, t2, t3);
    t0 = n0; t1 = n1; t2 = n2; t3 = n3;
}

// Merge quad-partner top-4 lists in-register (lanes l and l^mask hold lists
// for the same query when mask is 16 or 32).
__device__ __forceinline__ void merge_shfl(float& t0, float& t1, float& t2, float& t3, int mask) {
    float o0 = __shfl_xor(t0, mask), o1 = __shfl_xor(t1, mask);
    float o2 = __shfl_xor(t2, mask), o3 = __shfl_xor(t3, mask);
    top4L_insert(o0, t0, t1, t2, t3);
    top4L_insert(o1, t0, t1, t2, t3);
    top4L_insert(o2, t0, t1, t2, t3);
    top4L_insert(o3, t0, t1, t2, t3);
}

__device__ __forceinline__ unsigned short f32_to_bf16_rne(float x) {
    unsigned u = __float_as_uint(x);
    unsigned r = u + 0x7FFFu + ((u >> 16) & 1u);
    return (unsigned short)(r >> 16);
}

// K1: bf16 conversion of P,Q + norms pre-scaled by -0.5 ( -|x|^2/2 ).
__global__ void prep_kernel(const float* __restrict__ P, const float* __restrict__ Q,
                            unsigned short* __restrict__ Phi, unsigned short* __restrict__ Qhi,
                            float* __restrict__ normP, float* __restrict__ normQ) {
    int t = blockIdx.x * 256 + threadIdx.x;          // 0 .. 65535
    int mat = t >> 15;                               // 0 = P, 1 = Q
    int idx = t & 32767;
    int r = idx >> 2, seg = idx & 3;                 // 8 elements per thread
    const float* X = mat ? Q : P;
    unsigned short* Xhi = mat ? Qhi : Phi;
    float* nX = mat ? normQ : normP;

    const float* src = X + (size_t)r * DIMS + seg * 8;
    float4 v0 = *(const float4*)(src);
    float4 v1 = *(const float4*)(src + 4);
    float f[8] = {v0.x, v0.y, v0.z, v0.w, v1.x, v1.y, v1.z, v1.w};

    float p = 0.f;
#pragma unroll
    for (int k = 0; k < 8; ++k) p = fmaf(f[k], f[k], p);
    p += __shfl_xor(p, 1);
    p += __shfl_xor(p, 2);      // seg groups of 4 are lane-aligned
    if (seg == 0) nX[r] = -0.5f * p;

    unsigned short h[8];
#pragma unroll
    for (int k = 0; k < 8; ++k) h[k] = f32_to_bf16_rne(f[k]);
    uint4 ph;
    ph.x = (unsigned)h[0] | ((unsigned)h[1] << 16);
    ph.y = (unsigned)h[2] | ((unsigned)h[3] << 16);
    ph.z = (unsigned)h[4] | ((unsigned)h[5] << 16);
    ph.w = (unsigned)h[6] | ((unsigned)h[7] << 16);
    *(uint4*)(Xhi + (size_t)r * DIMS + seg * 8) = ph;
}

// K2: kNN partials. grid (MPTS/QB, 2 mats, ZSP) = 1024 blocks, 512 thr =
// 8 waves, launch_bounds(512,6) -> 3 blocks/CU (24 waves), VGPR cap ~85 so
// the g=4 body (4 B-frags/lane, round-7 codegen) fits WITHOUT spill.
// Wave w scans rows [z*2048 + w*256, +256): 8 iters x 32 rows; per iter
// 4 loads feed 8 MFMAs -> 32 inserts. s-domain: s = dot - na/2 (larger ==
// closer; per-query shift nb is ranking-exact). Quad lists merged in-wave
// (shfl_xor 16/32); 8 wave-lists merged in LDS -> parts[(mat*ZSP+z)][query].
__global__ __launch_bounds__(512, 6)
void knn_mfma(const unsigned short* __restrict__ Phi, const unsigned short* __restrict__ Qhi,
              const float* __restrict__ normP, const float* __restrict__ normQ,
              float4* __restrict__ parts) {
    __shared__ float4 ldsM[QB * 9];      // 9.2 KB: [query][wave], +1 pad
    const unsigned short* Yhi; const float* nY; int mat;
    if (blockIdx.y == 0) { Yhi = Qhi; nY = normQ; mat = 0; }
    else                 { Yhi = Phi; nY = normP; mat = 1; }
    const int tid = threadIdx.x;
    const int w = tid >> 6, l = tid & 63, q = l & 15, quad = l >> 4;
    const int q0 = blockIdx.x * QB;
    const int z = blockIdx.z;

    bf16x8 bh[4];
#pragma unroll
    for (int b = 0; b < 4; ++b)
        bh[b] = *(const bf16x8*)(Yhi + (size_t)(q0 + b * 16 + q) * DIMS + quad * 8);

    float t0[4], t1[4], t2[4], t3[4];
#pragma unroll
    for (int b = 0; b < 4; ++b) t0[b] = t1[b] = t2[b] = t3[b] = -3.4e38f;

    const int c0 = z * (MPTS / ZSP) + w * 256;
    const unsigned short* pH = Yhi + ((size_t)c0 + q) * DIMS + quad * 8;
    const float* pN = nY + c0 + quad * 4;

    for (int i = 0; i < 8; ++i) {
        bf16x8 ah0 = *(const bf16x8*)(pH);
        float4 nA0 = *(const float4*)(pN);
        bf16x8 ah1 = *(const bf16x8*)(pH + 16 * DIMS);
        float4 nA1 = *(const float4*)(pN + 16);
        pH += 32 * DIMS; pN += 32;
        f32x4 c0v = {nA0.x, nA0.y, nA0.z, nA0.w};
        f32x4 c1v = {nA1.x, nA1.y, nA1.z, nA1.w};
#pragma unroll
        for (int b = 0; b < 4; ++b) {
            f32x4 a0 = __builtin_amdgcn_mfma_f32_16x16x32_bf16(ah0, bh[b], c0v, 0, 0, 0);
            f32x4 a1 = __builtin_amdgcn_mfma_f32_16x16x32_bf16(ah1, bh[b], c1v, 0, 0, 0);
#pragma unroll
            for (int r = 0; r < 4; ++r) top4L_insert(a0[r], t0[b], t1[b], t2[b], t3[b]);
#pragma unroll
            for (int r = 0; r < 4; ++r) top4L_insert(a1[r], t0[b], t1[b], t2[b], t3[b]);
        }
    }

    // in-wave quad merge: 4 lists -> 1 per (wave, query)
#pragma unroll
    for (int b = 0; b < 4; ++b) {
        merge_shfl(t0[b], t1[b], t2[b], t3[b], 16);
        merge_shfl(t0[b], t1[b], t2[b], t3[b], 32);
    }
    if (quad == 0) {
#pragma unroll
        for (int b = 0; b < 4; ++b)
            ldsM[(q + b * 16) * 9 + w] = make_float4(t0[b], t1[b], t2[b], t3[b]);
    }
    __syncthreads();
    if (tid < QB) {
        float a0 = -3.4e38f, a1 = a0, a2 = a0, a3 = a0;
#pragma unroll
        for (int c = 0; c < 8; ++c) {
            float4 v = ldsM[tid * 9 + c];
            top4L_insert(v.x, a0, a1, a2, a3);
            top4L_insert(v.y, a0, a1, a2, a3);
            top4L_insert(v.z, a0, a1, a2, a3);
            top4L_insert(v.w, a0, a1, a2, a3);
        }
        parts[(size_t)(mat * ZSP + z) * MPTS + q0 + tid] = make_float4(a0, a1, a2, a3);
    }
}

// K3: counts. grid (MPTS/QB, 2 dirs, ZSP), same shape/occupancy. dir 0:
// queries=Q, cands=P; dir 1: queries=P, cands=Q. Prologue merges ZSP partial
// lists -> nu^2 (z==0 writes nusq) + s-domain tau. Scans its candidate slice
// counting s >= tau; writes per-z partial counts (no atomics).
__global__ __launch_bounds__(512, 6)
void count_mfma(const unsigned short* __restrict__ Phi, const unsigned short* __restrict__ Qhi,
                const float* __restrict__ normP, const float* __restrict__ normQ,
                const float4* __restrict__ parts,
                float* __restrict__ nusqP, float* __restrict__ nusqQ,
                int* __restrict__ cntPart) {
    __shared__ int   ldsC[QB * 9];
    __shared__ float ldsTau[QB];
    const unsigned short *Ahi, *Bhi; const float *nCand, *nQry; float* nusqOut;
    const int dir = blockIdx.y;
    if (dir == 0) { Ahi = Phi; Bhi = Qhi; nCand = normP; nQry = normQ; nusqOut = nusqQ; }
    else          { Ahi = Qhi; Bhi = Phi; nCand = normQ; nQry = normP; nusqOut = nusqP; }
    const int tid = threadIdx.x;
    const int w = tid >> 6, l = tid & 63, q = l & 15, quad = l >> 4;
    const int q0 = blockIdx.x * QB;
    const int z = blockIdx.z;

    if (tid < QB) {
        int qq = q0 + tid;
        const float4* base = parts + (size_t)dir * ZSP * MPTS;
        float4 f0 = base[qq];
        float a0 = f0.x, a1 = f0.y, a2 = f0.z, a3 = f0.w;     // desc
#pragma unroll
        for (int s = 1; s < ZSP; ++s) {
            float4 f1 = base[(size_t)s * MPTS + qq];
            top4L_insert(f1.x, a0, a1, a2, a3);
            top4L_insert(f1.y, a0, a1, a2, a3);
            top4L_insert(f1.z, a0, a1, a2, a3);
            top4L_insert(f1.w, a0, a1, a2, a3);
        }
        float nb = -2.0f * nQry[qq];                 // |q|^2
        float nu2 = fmaxf(nb - 2.0f * a3, 1e-12f);   // sq-domain nu^2, clamped
        if (z == 0) nusqOut[qq] = nu2;
        ldsTau[tid] = 0.5f * (nb - nu2);             // s-domain threshold
    }
    bf16x8 bh[4];
#pragma unroll
    for (int b = 0; b < 4; ++b)
        bh[b] = *(const bf16x8*)(Bhi + (size_t)(q0 + b * 16 + q) * DIMS + quad * 8);
    __syncthreads();
    float tau[4];
#pragma unroll
    for (int b = 0; b < 4; ++b) tau[b] = ldsTau[q + b * 16];

    int cnt[4] = {0, 0, 0, 0};
    const int c0 = z * (MPTS / ZSP) + w * 256;
    const unsigned short* pH = Ahi + ((size_t)c0 + q) * DIMS + quad * 8;
    const float* pN = nCand + c0 + quad * 4;

    for (int i = 0; i < 8; ++i) {
        bf16x8 ah0 = *(const bf16x8*)(pH);
        float4 nA0 = *(const float4*)(pN);
        bf16x8 ah1 = *(const bf16x8*)(pH + 16 * DIMS);
        float4 nA1 = *(const float4*)(pN + 16);
        pH += 32 * DIMS; pN += 32;
        f32x4 c0v = {nA0.x, nA0.y, nA0.z, nA0.w};
        f32x4 c1v = {nA1.x, nA1.y, nA1.z, nA1.w};
#pragma unroll
        for (int b = 0; b < 4; ++b) {
            f32x4 a0 = __builtin_amdgcn_mfma_f32_16x16x32_bf16(ah0, bh[b], c0v, 0, 0, 0);
            f32x4 a1 = __builtin_amdgcn_mfma_f32_16x16x32_bf16(ah1, bh[b], c1v, 0, 0, 0);
#pragma unroll
            for (int r = 0; r < 4; ++r) {
                cnt[b] += (a0[r] >= tau[b]) ? 1 : 0;
                cnt[b] += (a1[r] >= tau[b]) ? 1 : 0;
            }
        }
    }
#pragma unroll
    for (int b = 0; b < 4; ++b) {
        cnt[b] += __shfl_xor(cnt[b], 16);
        cnt[b] += __shfl_xor(cnt[b], 32);
    }
    if (quad == 0) {
#pragma unroll
        for (int b = 0; b < 4; ++b) ldsC[(q + b * 16) * 9 + w] = cnt[b];
    }
    __syncthreads();
    if (tid < QB) {
        int s = 0;
#pragma unroll
        for (int c = 0; c < 8; ++c) s += ldsC[tid * 9 + c];
        cntPart[(size_t)(dir * ZSP + z) * MPTS + q0 + tid] = s;
    }
}

// K4: epilogue; sums ZSP count partials; exact fp32 clip/pow semantics.
__global__ __launch_bounds__(512)
void final_kernel(const int* __restrict__ cntPart,
                  const float* __restrict__ nusqP, const float* __restrict__ nusqQ,
                  float* __restrict__ out) {
    __shared__ int    riQ[8], riP[8];
    __shared__ double rdQ[8], rdP[8];
    const int tid = threadIdx.x;
    const int w = tid >> 6, l = tid & 63;

    int sQ = 0, sP = 0;
    for (int j = tid; j < MPTS; j += 512) {
        int cq = 0, cp = 0;
#pragma unroll
        for (int zz = 0; zz < ZSP; ++zz) {
            cq += cntPart[(size_t)zz * MPTS + j];
            cp += cntPart[(size_t)(ZSP + zz) * MPTS + j];
        }
        sQ += cq; sP += cp;
    }
#pragma unroll
    for (int o = 32; o > 0; o >>= 1) { sQ += __shfl_down(sQ, o); sP += __shfl_down(sP, o); }
    if (l == 0) { riQ[w] = sQ; riP[w] = sP; }
    __syncthreads();
    int totQ = 0, totP = 0;
#pragma unroll
    for (int u = 0; u < 8; ++u) { totQ += riQ[u]; totP += riP[u]; }

    const float kq_term = 3.0f / 24576.0f;
    float kpQ = (float)totQ + 1e-20f;
    float kpP = (float)totP + 1e-20f;
    double rQ = 0.0, rP = 0.0;
    for (int j = tid; j < MPTS; j += 512) {
        int cq = 0, cp = 0;
#pragma unroll
        for (int zz = 0; zz < ZSP; ++zz) {
            cq += cntPart[(size_t)zz * MPTS + j];
            cp += cntPart[(size_t)(ZSP + zz) * MPTS + j];
        }
        {
            float nu = sqrtf(nusqQ[j]);
            float x = nu * nu; x *= x; x *= x; x *= x; x *= x;   // nu^32
            float inv = 1.0f / (x + 1e-20f);
            float p_den = ((float)cq / kpQ) * inv;
            p_den = fminf(fmaxf(p_den, 1e-20f), 1e10f);
            float q_den = kq_term * inv;
            q_den = fminf(fmaxf(q_den, 1e-20f), 1e10f);
            rQ += (double)((p_den / q_den) * kq_term);
        }
        {
            float nu = sqrtf(nusqP[j]);
            float x = nu * nu; x *= x; x *= x; x *= x; x *= x;
            float inv = 1.0f / (x + 1e-20f);
            float p_den = ((float)cp / kpP) * inv;
            p_den = fminf(fmaxf(p_den, 1e-20f), 1e10f);
            float q_den = kq_term * inv;
            q_den = fminf(fmaxf(q_den, 1e-20f), 1e10f);
            rP += (double)((p_den / q_den) * kq_term);
        }
    }
#pragma unroll
    for (int o = 32; o > 0; o >>= 1) { rQ += __shfl_down(rQ, o); rP += __shfl_down(rP, o); }
    if (l == 0) { rdQ[w] = rQ; rdP[w] = rP; }
    __syncthreads();
    if (tid == 0) {
        double RQ = 0.0, RP = 0.0;
#pragma unroll
        for (int u = 0; u < 8; ++u) { RQ += rdQ[u]; RP += rdP[u]; }
        float divP = fmaxf(0.0f, logf((float)RQ));    // alpha=2 -> 1/(alpha-1)=1
        float divQ = fmaxf(0.0f, logf((float)RP));
        out[0] = fmaxf(divP, divQ);
    }
}

extern "C" void kernel_launch(void* const* d_in, const int* in_sizes, int n_in,
                              void* d_out, int out_size, void* d_ws, size_t ws_size,
                              hipStream_t stream) {
    const float* P = (const float*)d_in[0];
    const float* Q = (const float*)d_in[1];
    float* out = (float*)d_out;

    unsigned short* Phi = (unsigned short*)d_ws;
    unsigned short* Qhi = Phi + MPTS * DIMS;
    float* normP = (float*)(Qhi + MPTS * DIMS);
    float* normQ = normP + MPTS;
    float4* parts = (float4*)(normQ + MPTS);             // 2 mats x ZSP x MPTS
    float* nusqP = (float*)(parts + 2 * ZSP * MPTS);
    float* nusqQ = nusqP + MPTS;
    int* cntPart = (int*)(nusqQ + MPTS);                 // 2 dirs x ZSP x MPTS

    prep_kernel<<<256, 256, 0, stream>>>(P, Q, Phi, Qhi, normP, normQ);
    knn_mfma<<<dim3(MPTS / QB, 2, ZSP), 512, 0, stream>>>(Phi, Qhi, normP, normQ, parts);
    count_mfma<<<dim3(MPTS / QB, 2, ZSP), 512, 0, stream>>>(Phi, Qhi, normP, normQ, parts,
                                                            nusqP, nusqQ, cntPart);
    final_kernel<<<1, 512, 0, stream>>>(cntPart, nusqP, nusqQ, out);
}